// Round 8
// baseline (479.562 us; speedup 1.0000x reference)
//
#include <hip/hip_runtime.h>
#include <math.h>

// LightweightConv1dTBC: out[t,b,c] = sum_k x[t-15+k, b, c] * softmax(w[h(c),:])[k] + bias[c]
// T=2048 B=8 C=1024 H=16 K=31 P=15, R = C/H = 64 channels per head.
//
// R7: R3 structure (scalar coalesced loads, wave-uniform SGPR weights, NT
// stores) with STRIP=32: halo re-read 2.875x -> 1.94x, 62 independent loads
// of ILP per thread, and total work = 8192 waves = ONE full-occupancy cohort
// (32 waves/CU) when VGPR<=64. waves_per_eu(6,8) gives an 85-reg budget so
// the ~55 live regs cannot spill (R4/R5 lesson). z-major XCD swizzle keeps
// halo-sharing neighbor strips on the same XCD L2.

#define T_DIM 2048
#define B_DIM 8
#define C_DIM 1024
#define H_DIM 16
#define K_DIM 31
#define P_PAD 15
#define STRIP 32
#define NWG ((C_DIM / 256) * B_DIM * (T_DIM / STRIP))   // 4*8*64 = 2048 blocks

template<bool CHECK>
__device__ __forceinline__ void run_strip(const float* __restrict__ xb,
                                          float* __restrict__ ob,
                                          const float (&w)[K_DIM],
                                          float bv, int t0)
{
    float acc[STRIP];
    #pragma unroll
    for (int i = 0; i < STRIP; ++i) acc[i] = bv;

    #pragma unroll
    for (int r = 0; r < STRIP + K_DIM - 1; ++r) {   // 62 streamed inputs
        const int t = t0 - P_PAD + r;
        float xv = 0.f;
        if (!CHECK || ((unsigned)t < (unsigned)T_DIM)) {
            xv = xb[(size_t)t * (B_DIM * C_DIM)];
        }
        #pragma unroll
        for (int i = 0; i < STRIP; ++i) {
            const int k = r - i;
            if (k >= 0 && k < K_DIM) {              // folds statically
                acc[i] = fmaf(xv, w[k], acc[i]);
            }
        }
    }

    #pragma unroll
    for (int i = 0; i < STRIP; ++i) {
        __builtin_nontemporal_store(acc[i], &ob[(size_t)(t0 + i) * (B_DIM * C_DIM)]);
    }
}

__global__ __launch_bounds__(256)
__attribute__((amdgpu_waves_per_eu(6, 8)))
void lwconv_tbc_kernel(
    const float* __restrict__ x,       // (T, B, C)
    const float* __restrict__ weight,  // (H, 1, K)
    const float* __restrict__ bias,    // (C,)
    float* __restrict__ out)           // (T, B, C)
{
    const int tid  = threadIdx.x;
    const int lane = tid & 63;

    // --- z-major XCD swizzle: XCD gets 256 consecutive (cTile,b,z) items,
    //     z fastest -> halo-sharing neighbors on same XCD L2 ---
    const int bid = blockIdx.x;
    const int swz = (bid & 7) * (NWG / 8) + (bid >> 3);
    const int z     = swz & 63;          // t strip
    const int b     = (swz >> 6) & 7;    // batch
    const int cTile = swz >> 9;          // 0..3
    const int t0 = z * STRIP;
    const int c  = cTile * 256 + tid;    // lanes contiguous in C
    const int h  = c >> 6;               // one head per wave (R=64)

    // --- wave-level softmax of this head's 31 weights ---
    float wv = -1e30f;
    if (lane < K_DIM) wv = weight[h * K_DIM + lane];
    float m = wv;
    #pragma unroll
    for (int off = 32; off; off >>= 1) m = fmaxf(m, __shfl_xor(m, off));
    float e = (lane < K_DIM) ? expf(wv - m) : 0.f;
    float s = e;
    #pragma unroll
    for (int off = 32; off; off >>= 1) s += __shfl_xor(s, off);
    const float p = e / s;

    // broadcast to SGPRs (wave-uniform weights)
    float w[K_DIM];
    #pragma unroll
    for (int k = 0; k < K_DIM; ++k) {
        union { float f; int i; } u;
        u.f = p;
        u.i = __builtin_amdgcn_readlane(u.i, k);
        w[k] = u.f;
    }

    const float bv = bias[c];
    const float* xb = x + (size_t)b * C_DIM + c;
    float* ob = out + (size_t)b * C_DIM + c;

    // interior strips need rows t0-15 .. t0+STRIP-1+15 all in [0, T)
    const bool interior = (t0 >= P_PAD) && (t0 + STRIP - 1 + K_DIM - 1 - P_PAD < T_DIM);
    if (interior) run_strip<false>(xb, ob, w, bv, t0);
    else          run_strip<true >(xb, ob, w, bv, t0);
}

extern "C" void kernel_launch(void* const* d_in, const int* in_sizes, int n_in,
                              void* d_out, int out_size, void* d_ws, size_t ws_size,
                              hipStream_t stream) {
    const float* x      = (const float*)d_in[0];
    const float* weight = (const float*)d_in[1];
    const float* bias   = (const float*)d_in[2];
    float* out = (float*)d_out;

    lwconv_tbc_kernel<<<dim3(NWG), dim3(256), 0, stream>>>(x, weight, bias, out);
}

// Round 9
// 29.138 us; speedup vs baseline: 16.4583x; 16.4583x over previous
//
#include <hip/hip_runtime.h>
#include <math.h>

// LightweightConv1dTBC: out[t,b,c] = sum_k x[t-15+k, b, c] * softmax(w[h(c),:])[k] + bias[c]
// T=2048 B=8 C=1024 H=16 K=31 P=15, R = C/H = 64 channels per head.
//
// R8 = R3 (best: 28.8us) + two-phase strip: prefetch ALL 46 x-values into a
// statically-indexed register window, sched_barrier, then the FMA phase.
// 46 outstanding loads/wave hides HBM latency even at 4 waves/EU.
// Register budget via amdgpu_waves_per_eu(2,4) -- the ONLY hint observed to
// raise the VGPR budget (R6: 108 regs, no spill). R4/R5/R7 all spilled with
// launch_bounds minimums or (6,8).

#define T_DIM 2048
#define B_DIM 8
#define C_DIM 1024
#define H_DIM 16
#define K_DIM 31
#define P_PAD 15
#define STRIP 16
#define WIN (STRIP + K_DIM - 1)   // 46

template<bool CHECK>
__device__ __forceinline__ void run_strip(const float* __restrict__ xb,
                                          float* __restrict__ ob,
                                          const float (&w)[K_DIM],
                                          float bv, int t0)
{
    // phase 1: all 46 loads issued back-to-back (static indices -> registers)
    float xr[WIN];
    #pragma unroll
    for (int r = 0; r < WIN; ++r) {
        const int t = t0 - P_PAD + r;
        float xv = 0.f;
        if (!CHECK || ((unsigned)t < (unsigned)T_DIM)) {
            xv = xb[(size_t)t * (B_DIM * C_DIM)];
        }
        xr[r] = xv;
    }
    __builtin_amdgcn_sched_barrier(0);   // keep loads above the FMA phase

    // phase 2: 496 FMAs
    float acc[STRIP];
    #pragma unroll
    for (int i = 0; i < STRIP; ++i) acc[i] = bv;

    #pragma unroll
    for (int r = 0; r < WIN; ++r) {
        const float xv = xr[r];
        #pragma unroll
        for (int i = 0; i < STRIP; ++i) {
            const int k = r - i;
            if (k >= 0 && k < K_DIM) {          // folds statically
                acc[i] = fmaf(xv, w[k], acc[i]);
            }
        }
    }

    #pragma unroll
    for (int i = 0; i < STRIP; ++i) {
        __builtin_nontemporal_store(acc[i], &ob[(size_t)(t0 + i) * (B_DIM * C_DIM)]);
    }
}

__global__ __launch_bounds__(256)
__attribute__((amdgpu_waves_per_eu(2, 4)))
void lwconv_tbc_kernel(
    const float* __restrict__ x,       // (T, B, C)
    const float* __restrict__ weight,  // (H, 1, K)
    const float* __restrict__ bias,    // (C,)
    float* __restrict__ out)           // (T, B, C)
{
    const int tid  = threadIdx.x;
    const int lane = tid & 63;
    const int c    = blockIdx.x * 256 + tid;   // lanes contiguous in C
    const int h    = c >> 6;                   // one head per wave (R=64)
    const int b    = blockIdx.y;
    const int t0   = blockIdx.z * STRIP;

    // --- wave-level softmax of this head's 31 weights ---
    float wv = -1e30f;
    if (lane < K_DIM) wv = weight[h * K_DIM + lane];
    float m = wv;
    #pragma unroll
    for (int off = 32; off; off >>= 1) m = fmaxf(m, __shfl_xor(m, off));
    float e = (lane < K_DIM) ? expf(wv - m) : 0.f;
    float s = e;
    #pragma unroll
    for (int off = 32; off; off >>= 1) s += __shfl_xor(s, off);
    const float p = e / s;

    // broadcast to SGPRs (wave-uniform weights)
    float w[K_DIM];
    #pragma unroll
    for (int k = 0; k < K_DIM; ++k) {
        union { float f; int i; } u;
        u.f = p;
        u.i = __builtin_amdgcn_readlane(u.i, k);
        w[k] = u.f;
    }

    const float bv = bias[c];
    const float* xb = x + (size_t)b * C_DIM + c;
    float* ob = out + (size_t)b * C_DIM + c;

    // interior strips need rows t0-15 .. t0+STRIP-1+15 all in [0, T)
    const bool interior = (t0 >= P_PAD) && (t0 + STRIP - 1 + K_DIM - 1 - P_PAD < T_DIM);
    if (interior) run_strip<false>(xb, ob, w, bv, t0);
    else          run_strip<true >(xb, ob, w, bv, t0);
}

extern "C" void kernel_launch(void* const* d_in, const int* in_sizes, int n_in,
                              void* d_out, int out_size, void* d_ws, size_t ws_size,
                              hipStream_t stream) {
    const float* x      = (const float*)d_in[0];
    const float* weight = (const float*)d_in[1];
    const float* bias   = (const float*)d_in[2];
    float* out = (float*)d_out;

    dim3 grid(C_DIM / 256, B_DIM, T_DIM / STRIP);   // (4, 8, 128) = 4096 blocks
    dim3 block(256);
    lwconv_tbc_kernel<<<grid, block, 0, stream>>>(x, weight, bias, out);
}